// Round 2
// baseline (573.417 us; speedup 1.0000x reference)
//
#include <hip/hip_runtime.h>
#include <stdint.h>

#define N_NODES 50000
#define N_EDGES 1600000
#define HID 128
#define NREL1 9   // 8 relations + self-loop folded in as pseudo-relation 8
#define NB 196    // dst buckets of 256 nodes
#define NSUB 8    // sub-counters per bucket (atomic contention relief)
#define NB2 (NB * NSUB)

typedef float f32x4 __attribute__((ext_vector_type(4)));
typedef short s16x8 __attribute__((ext_vector_type(8)));

__device__ __forceinline__ unsigned short f2bf(float f) {
  unsigned u = __float_as_uint(f);
  u += 0x7fffu + ((u >> 16) & 1u);   // RNE
  return (unsigned short)(u >> 16);
}

// ---- W transpose + convert: Wt[l][r][k][d] = W[l][r][d][k] (r=8 -> W_loop) ----
__global__ void k_convert_w(const float* __restrict__ W, const float* __restrict__ Wl,
                            unsigned short* __restrict__ Wt) {
  int idx = blockIdx.x * 256 + threadIdx.x;   // (((l*9+r)*128)+k)*128+d
  int d  = idx & 127;
  int k  = (idx >> 7) & 127;
  int lr = idx >> 14;                          // l*9 + r
  int l = lr / 9, r = lr - l * 9;
  float v;
  if (r < 8) v = W[((((size_t)l * 8 + r) * 128) + d) * 128 + k];
  else       v = Wl[(((size_t)l * 128) + d) * 128 + k];
  Wt[idx] = f2bf(v);
}

// ---- h0 = bf16(emb[node_id]) ----
__global__ void k_gather_h0(const int* __restrict__ nid, const float* __restrict__ emb,
                            unsigned short* __restrict__ h0) {
  int t = blockIdx.x * 256 + threadIdx.x;      // N*32 threads, 4 elems each
  int i = t >> 5, c = (t & 31) * 4;
  if (i >= N_NODES) return;
  const float4 v = *(const float4*)(emb + (size_t)nid[i] * HID + c);
  ushort4 o;
  o.x = f2bf(v.x); o.y = f2bf(v.y); o.z = f2bf(v.z); o.w = f2bf(v.w);
  *(ushort4*)(h0 + (size_t)i * HID + c) = o;
}

__device__ __forceinline__ int block_scan_excl(int v, int t) {
  const int lane = t & 63, wid = t >> 6;
  int incl = v;
  #pragma unroll
  for (int o = 1; o < 64; o <<= 1) {
    int nv = __shfl_up(incl, o);
    if (lane >= o) incl += nv;
  }
  __shared__ int wsum[4];
  if (lane == 63) wsum[wid] = incl;
  __syncthreads();
  int wbase = 0;
  #pragma unroll
  for (int w = 0; w < 3; ++w) if (w < wid) wbase += wsum[w];
  return wbase + incl - v;
}

// ---- CSR build, pass A: bucket histogram (LDS-staged, 1568 counters) ----
__global__ void k_bucket_hist(const int* __restrict__ dst, int* __restrict__ gcnt) {
  __shared__ int h[NB2];
  for (int i = threadIdx.x; i < NB2; i += 256) h[i] = 0;
  __syncthreads();
  int base = blockIdx.x * 8192;
  for (int i = threadIdx.x; i < 8192; i += 256) {
    int e = base + i;
    if (e < N_EDGES) {
      int b2 = (dst[e] >> 8) * NSUB + ((e >> 8) & (NSUB - 1));
      atomicAdd(&h[b2], 1);
    }
  }
  __syncthreads();
  for (int i = threadIdx.x; i < NB2; i += 256) {
    int v = h[i];
    if (v) atomicAdd(&gcnt[i], v);
  }
}

// ---- CSR build, scan over 1568 counters (single WG) ----
__global__ void k_bucket_scan(const int* __restrict__ gcnt, int* __restrict__ bfill,
                              int* __restrict__ bbase, int* __restrict__ rowptr) {
  int t = threadIdx.x;
  int lo = t * 7;                      // 7 per thread covers 1792 >= 1568
  int v[7];
  int s = 0;
  #pragma unroll
  for (int j = 0; j < 7; ++j) { int i = lo + j; v[j] = (i < NB2) ? gcnt[i] : 0; s += v[j]; }
  int ex = block_scan_excl(s, t);
  int run = ex;
  #pragma unroll
  for (int j = 0; j < 7; ++j) { int i = lo + j; if (i < NB2) bfill[i] = run; run += v[j]; }
  __syncthreads();
  for (int i = t; i < NB; i += 256) bbase[i] = bfill[i * NSUB];
  if (t == 0) { bbase[NB] = N_EDGES; rowptr[N_NODES] = N_EDGES; }
}

// ---- CSR build, pass B: binned scatter of packed records into tmp ----
// record = (dst&255)<<19 | et<<16 | src   (8+3+16 = 27 bits)
__global__ void k_bucket_scatter(const int* __restrict__ src, const int* __restrict__ dst,
                                 const int* __restrict__ et, int* __restrict__ bfill,
                                 unsigned* __restrict__ tmp) {
  int e = blockIdx.x * 256 + threadIdx.x;
  if (e >= N_EDGES) return;
  int d = dst[e];
  int b2 = (d >> 8) * NSUB + ((e >> 8) & (NSUB - 1));
  int pos = atomicAdd(&bfill[b2], 1);
  tmp[pos] = ((unsigned)(d & 255) << 19) | ((unsigned)et[e] << 16) | (unsigned)src[e];
}

// ---- CSR build, pass C: per-bucket local counting sort -> rowptr + keys ----
__global__ void k_bucket_finalize(const unsigned* __restrict__ tmp,
                                  const int* __restrict__ bbase,
                                  int* __restrict__ rowptr, unsigned* __restrict__ keys) {
  __shared__ int cnt[256];
  __shared__ int off[256];
  const int b = blockIdx.x;
  const int t = threadIdx.x;
  const int s = bbase[b], e = bbase[b + 1];
  cnt[t] = 0;
  __syncthreads();
  for (int i = s + t; i < e; i += 256)
    atomicAdd(&cnt[tmp[i] >> 19], 1);
  __syncthreads();
  int ex = block_scan_excl(cnt[t], t);
  int node = b * 256 + t;
  if (node < N_NODES) rowptr[node] = s + ex;
  off[t] = s + ex;
  __syncthreads();
  for (int i = s + t; i < e; i += 256) {
    unsigned r = tmp[i];
    int pos = atomicAdd(&off[r >> 19], 1);
    keys[pos] = ((r >> 16) & 7u) * N_NODES + (r & 0xffffu);
  }
}

// ---- GEMM: X[rel][n][k] = sum_d A[n][d] * Wt[rel][k][d], bf16 in/out, f32 acc ----
__global__ __launch_bounds__(256, 2) void k_gemm(
    const unsigned short* __restrict__ A,   // [N][128] bf16
    const unsigned short* __restrict__ Bw,  // [9][128][128] bf16 (this layer's Wt)
    unsigned short* __restrict__ X) {       // [9][N][128] bf16
  __shared__ unsigned char lds[65536];
  unsigned char* As = lds;
  unsigned char* Bs = lds + 32768;
  const int t   = threadIdx.x;
  const int rel = blockIdx.x;
  const int mb  = blockIdx.y;
  const unsigned char* Asrc = (const unsigned char*)A;
  const unsigned char* Bsrc = (const unsigned char*)(Bw + (size_t)rel * (128 * 128));
  #pragma unroll
  for (int c = 0; c < 8; ++c) {
    int off = c * 4096 + t * 16;
    int row = off >> 8;
    int ib  = off & 255;
    int swz = ib ^ ((row & 7) << 4);
    int grow = mb * 128 + row;
    uint4 va = make_uint4(0u, 0u, 0u, 0u);
    if (grow < N_NODES) va = *(const uint4*)(Asrc + (size_t)grow * 256 + ib);
    *(uint4*)(As + row * 256 + swz) = va;
    uint4 vb = *(const uint4*)(Bsrc + off);
    *(uint4*)(Bs + row * 256 + swz) = vb;
  }
  __syncthreads();
  const int wid = t >> 6, lane = t & 63;
  const int row0 = wid * 32;
  const int lr = lane & 15;
  const int kg = (lane >> 4) * 8;
  f32x4 acc[2][8];
  #pragma unroll
  for (int m = 0; m < 2; ++m)
    #pragma unroll
    for (int n = 0; n < 8; ++n) acc[m][n] = (f32x4)(0.f);
  #pragma unroll
  for (int kk = 0; kk < 4; ++kk) {
    const int kb = (kk * 32 + kg) * 2;
    s16x8 a[2], b[8];
    #pragma unroll
    for (int m = 0; m < 2; ++m) {
      int r = row0 + m * 16 + lr;
      a[m] = *(const s16x8*)(As + r * 256 + (kb ^ ((r & 7) << 4)));
    }
    #pragma unroll
    for (int n = 0; n < 8; ++n) {
      int cc = n * 16 + lr;
      b[n] = *(const s16x8*)(Bs + cc * 256 + (kb ^ ((cc & 7) << 4)));
    }
    #pragma unroll
    for (int m = 0; m < 2; ++m)
      #pragma unroll
      for (int n = 0; n < 8; ++n)
        acc[m][n] = __builtin_amdgcn_mfma_f32_16x16x32_bf16(a[m], b[n], acc[m][n], 0, 0, 0);
  }
  #pragma unroll
  for (int m = 0; m < 2; ++m) {
    int rbase = mb * 128 + row0 + m * 16 + (lane >> 4) * 4;
    #pragma unroll
    for (int n = 0; n < 8; ++n) {
      int col = n * 16 + lr;
      #pragma unroll
      for (int j = 0; j < 4; ++j) {
        int grow = rbase + j;
        if (grow < N_NODES)
          X[((size_t)rel * N_NODES + grow) * 128 + col] = f2bf(acc[m][n][j]);
      }
    }
  }
}

// ---- per-node aggregation over CSR: one wave per node, 2 f32 acc cols/lane ----
template <bool LAST>
__global__ void k_aggregate(const unsigned short* __restrict__ X,
                            const unsigned* __restrict__ keys,
                            const int* __restrict__ rowptr,
                            const float* __restrict__ bias,
                            void* __restrict__ out) {
  const int t = threadIdx.x;
  const int v = blockIdx.x * 4 + (t >> 6);
  const int lane = t & 63;
  const int start = rowptr[v], end = rowptr[v + 1];
  const unsigned char* Xb = (const unsigned char*)X;
  float a0 = 0.f, a1 = 0.f;
  int e = start;
  int nend = start + ((end - start) & ~3);
  for (; e < nend; e += 4) {
    unsigned k0 = keys[e], k1 = keys[e + 1], k2 = keys[e + 2], k3 = keys[e + 3];
    unsigned p0 = *(const unsigned*)(Xb + ((size_t)k0 << 8) + lane * 4);
    unsigned p1 = *(const unsigned*)(Xb + ((size_t)k1 << 8) + lane * 4);
    unsigned p2 = *(const unsigned*)(Xb + ((size_t)k2 << 8) + lane * 4);
    unsigned p3 = *(const unsigned*)(Xb + ((size_t)k3 << 8) + lane * 4);
    a0 += __uint_as_float(p0 << 16); a1 += __uint_as_float(p0 & 0xffff0000u);
    a0 += __uint_as_float(p1 << 16); a1 += __uint_as_float(p1 & 0xffff0000u);
    a0 += __uint_as_float(p2 << 16); a1 += __uint_as_float(p2 & 0xffff0000u);
    a0 += __uint_as_float(p3 << 16); a1 += __uint_as_float(p3 & 0xffff0000u);
  }
  for (; e < end; ++e) {
    unsigned k = keys[e];
    unsigned p = *(const unsigned*)(Xb + ((size_t)k << 8) + lane * 4);
    a0 += __uint_as_float(p << 16); a1 += __uint_as_float(p & 0xffff0000u);
  }
  { // self-loop pseudo-relation row
    unsigned p = *(const unsigned*)(Xb + (((size_t)8 * N_NODES + v) << 8) + lane * 4);
    a0 += __uint_as_float(p << 16); a1 += __uint_as_float(p & 0xffff0000u);
  }
  const float2 bb = *(const float2*)(bias + lane * 2);
  a0 += bb.x; a1 += bb.y;
  if (LAST) {
    float2 o; o.x = a0; o.y = a1;
    *(float2*)((float*)out + (size_t)v * 128 + lane * 2) = o;
  } else {
    unsigned po = ((unsigned)f2bf(a1) << 16) | (unsigned)f2bf(a0);
    *(unsigned*)((unsigned short*)out + (size_t)v * 128 + lane * 2) = po;
  }
}

extern "C" void kernel_launch(void* const* d_in, const int* in_sizes, int n_in,
                              void* d_out, int out_size, void* d_ws, size_t ws_size,
                              hipStream_t stream) {
  const int*   nid  = (const int*)d_in[0];
  const int*   src  = (const int*)d_in[1];
  const int*   dst  = (const int*)d_in[2];
  const int*   et   = (const int*)d_in[3];
  const float* emb  = (const float*)d_in[4];
  const float* W    = (const float*)d_in[5];
  const float* Wl   = (const float*)d_in[6];
  const float* bias = (const float*)d_in[7];

  unsigned char* ws = (unsigned char*)d_ws;
  size_t off = 0;
  auto alloc = [&](size_t bytes) {
    void* p = ws + off;
    off = (off + bytes + 255) & ~(size_t)255;
    return p;
  };
  unsigned short* X    = (unsigned short*)alloc((size_t)NREL1 * N_NODES * HID * 2); // 115.2 MB
  unsigned short* h0   = (unsigned short*)alloc((size_t)N_NODES * HID * 2);         // 12.8 MB
  unsigned short* h1   = (unsigned short*)alloc((size_t)N_NODES * HID * 2);         // 12.8 MB
  unsigned short* Wt   = (unsigned short*)alloc((size_t)2 * NREL1 * 128 * 128 * 2); // 0.6 MB
  unsigned*       keys = (unsigned*)alloc((size_t)N_EDGES * 4);                     // 6.4 MB
  int*            rowp = (int*)alloc((size_t)(N_NODES + 1) * 4);
  int*            gcnt = (int*)alloc((size_t)NB2 * 4);
  int*            bfil = (int*)alloc((size_t)NB2 * 4);
  int*            bbas = (int*)alloc((size_t)(NB + 1) * 4);
  unsigned*       tmp  = (unsigned*)X;   // X is dead until GEMM; reuse as 6.4MB scratch

  hipMemsetAsync(gcnt, 0, (size_t)NB2 * 4, stream);

  k_convert_w<<<1152, 256, 0, stream>>>(W, Wl, Wt);
  k_gather_h0<<<(N_NODES * 32) / 256, 256, 0, stream>>>(nid, emb, h0);
  k_bucket_hist<<<(N_EDGES + 8191) / 8192, 256, 0, stream>>>(dst, gcnt);
  k_bucket_scan<<<1, 256, 0, stream>>>(gcnt, bfil, bbas, rowp);
  k_bucket_scatter<<<(N_EDGES + 255) / 256, 256, 0, stream>>>(src, dst, et, bfil, tmp);
  k_bucket_finalize<<<NB, 256, 0, stream>>>(tmp, bbas, rowp, keys);

  dim3 ggrid(NREL1, (N_NODES + 127) / 128);
  // layer 0
  k_gemm<<<ggrid, 256, 0, stream>>>(h0, Wt, X);
  k_aggregate<false><<<N_NODES / 4, 256, 0, stream>>>(X, keys, rowp, bias, (void*)h1);
  // layer 1
  k_gemm<<<ggrid, 256, 0, stream>>>(h1, Wt + (size_t)NREL1 * 128 * 128, X);
  k_aggregate<true><<<N_NODES / 4, 256, 0, stream>>>(X, keys, rowp, bias + HID, (void*)d_out);
}

// Round 3
// 377.733 us; speedup vs baseline: 1.5181x; 1.5181x over previous
//
#include <hip/hip_runtime.h>
#include <stdint.h>

#define N_NODES 50000
#define N_EDGES 1600000
#define HID 128
#define NREL1 9   // 8 relations + self-loop folded in as pseudo-relation 8
#define NB 196    // dst buckets of 256 nodes
#define CHUNK 8192
#define NCH 196   // ceil(1600000 / 8192)
#define TOT (NB * NCH)

typedef float f32x4 __attribute__((ext_vector_type(4)));
typedef short s16x8 __attribute__((ext_vector_type(8)));

__device__ __forceinline__ unsigned short f2bf(float f) {
  unsigned u = __float_as_uint(f);
  u += 0x7fffu + ((u >> 16) & 1u);   // RNE
  return (unsigned short)(u >> 16);
}

// ---- W transpose + convert: Wt[l][r][k][d] = W[l][r][d][k] (r=8 -> W_loop) ----
__global__ void k_convert_w(const float* __restrict__ W, const float* __restrict__ Wl,
                            unsigned short* __restrict__ Wt) {
  int idx = blockIdx.x * 256 + threadIdx.x;   // (((l*9+r)*128)+k)*128+d
  int d  = idx & 127;
  int k  = (idx >> 7) & 127;
  int lr = idx >> 14;                          // l*9 + r
  int l = lr / 9, r = lr - l * 9;
  float v;
  if (r < 8) v = W[((((size_t)l * 8 + r) * 128) + d) * 128 + k];
  else       v = Wl[(((size_t)l * 128) + d) * 128 + k];
  Wt[idx] = f2bf(v);
}

// ---- h0 = bf16(emb[node_id]) ----
__global__ void k_gather_h0(const int* __restrict__ nid, const float* __restrict__ emb,
                            unsigned short* __restrict__ h0) {
  int t = blockIdx.x * 256 + threadIdx.x;      // N*32 threads, 4 elems each
  int i = t >> 5, c = (t & 31) * 4;
  if (i >= N_NODES) return;
  const float4 v = *(const float4*)(emb + (size_t)nid[i] * HID + c);
  ushort4 o;
  o.x = f2bf(v.x); o.y = f2bf(v.y); o.z = f2bf(v.z); o.w = f2bf(v.w);
  *(ushort4*)(h0 + (size_t)i * HID + c) = o;
}

__device__ __forceinline__ int block_scan_excl(int v, int t) {
  const int lane = t & 63, wid = t >> 6;
  int incl = v;
  #pragma unroll
  for (int o = 1; o < 64; o <<= 1) {
    int nv = __shfl_up(incl, o);
    if (lane >= o) incl += nv;
  }
  __shared__ int wsum[4];
  if (lane == 63) wsum[wid] = incl;
  __syncthreads();
  int wbase = 0;
  #pragma unroll
  for (int w = 0; w < 3; ++w) if (w < wid) wbase += wsum[w];
  return wbase + incl - v;
}

// ---- CSR pass A: per-chunk bucket histogram, LDS only, no global atomics ----
__global__ void k_chunk_hist(const int* __restrict__ dst, int* __restrict__ hist) {
  __shared__ int h[NB];
  const int c = blockIdx.x, t = threadIdx.x;
  if (t < NB) h[t] = 0;
  __syncthreads();
  int base = c * CHUNK;
  #pragma unroll 4
  for (int i = t; i < CHUNK; i += 256) {
    int e = base + i;
    if (e < N_EDGES) atomicAdd(&h[dst[e] >> 8], 1);
  }
  __syncthreads();
  if (t < NB) hist[c * NB + t] = h[t];
}

// ---- CSR pass B: exclusive scan of 196x196 counters, bucket-major order ----
// cur[c*NB+b] = start offset for (chunk c, bucket b); bbase[b] = bucket start
__global__ void k_csr_scan(const int* __restrict__ hist, int* __restrict__ cur,
                           int* __restrict__ bbase, int* __restrict__ rowptr) {
  const int t = threadIdx.x;
  const int J = (TOT + 255) / 256;      // 151
  const int lo = t * J;
  int s = 0;
  for (int j = 0; j < J; ++j) {
    int idx = lo + j;                   // linear = b*NCH + c
    if (idx < TOT) {
      int b = idx / NCH, c = idx - b * NCH;
      s += hist[c * NB + b];
    }
  }
  int run = block_scan_excl(s, t);
  for (int j = 0; j < J; ++j) {
    int idx = lo + j;
    if (idx < TOT) {
      int b = idx / NCH, c = idx - b * NCH;
      cur[c * NB + b] = run;
      if (c == 0) bbase[b] = run;
      run += hist[c * NB + b];
    }
  }
  if (t == 0) { bbase[NB] = N_EDGES; rowptr[N_NODES] = N_EDGES; }
}

// ---- CSR pass C: chunk-local scatter via LDS cursors (no global atomics) ----
// record = (dst&255)<<19 | et<<16 | src
__global__ void k_chunk_scatter(const int* __restrict__ src, const int* __restrict__ dst,
                                const int* __restrict__ et, const int* __restrict__ cur,
                                unsigned* __restrict__ tmp) {
  __shared__ int off2[NB];
  const int c = blockIdx.x, t = threadIdx.x;
  if (t < NB) off2[t] = cur[c * NB + t];
  __syncthreads();
  int base = c * CHUNK;
  #pragma unroll 4
  for (int i = t; i < CHUNK; i += 256) {
    int e = base + i;
    if (e < N_EDGES) {
      int d = dst[e];
      int pos = atomicAdd(&off2[d >> 8], 1);
      tmp[pos] = ((unsigned)(d & 255) << 19) | ((unsigned)et[e] << 16) | (unsigned)src[e];
    }
  }
}

// ---- CSR finalize: per-bucket local counting sort -> rowptr + keys ----
__global__ void k_bucket_finalize(const unsigned* __restrict__ tmp,
                                  const int* __restrict__ bbase,
                                  int* __restrict__ rowptr, unsigned* __restrict__ keys) {
  __shared__ int cnt[256];
  __shared__ int off[256];
  const int b = blockIdx.x;
  const int t = threadIdx.x;
  const int s = bbase[b], e = bbase[b + 1];
  cnt[t] = 0;
  __syncthreads();
  for (int i = s + t; i < e; i += 256)
    atomicAdd(&cnt[tmp[i] >> 19], 1);
  __syncthreads();
  int ex = block_scan_excl(cnt[t], t);
  int node = b * 256 + t;
  if (node < N_NODES) rowptr[node] = s + ex;
  off[t] = s + ex;
  __syncthreads();
  for (int i = s + t; i < e; i += 256) {
    unsigned r = tmp[i];
    int pos = atomicAdd(&off[r >> 19], 1);
    keys[pos] = ((r >> 16) & 7u) * N_NODES + (r & 0xffffu);
  }
}

// ---- GEMM: X[rel][n][k] = sum_d A[n][d] * Wt[rel][k][d], bf16 in/out, f32 acc ----
__global__ __launch_bounds__(256, 2) void k_gemm(
    const unsigned short* __restrict__ A,   // [N][128] bf16
    const unsigned short* __restrict__ Bw,  // [9][128][128] bf16 (this layer's Wt)
    unsigned short* __restrict__ X) {       // [9][N][128] bf16
  __shared__ unsigned char lds[65536];
  unsigned char* As = lds;
  unsigned char* Bs = lds + 32768;
  const int t   = threadIdx.x;
  const int rel = blockIdx.x;
  const int mb  = blockIdx.y;
  const unsigned char* Asrc = (const unsigned char*)A;
  const unsigned char* Bsrc = (const unsigned char*)(Bw + (size_t)rel * (128 * 128));
  #pragma unroll
  for (int c = 0; c < 8; ++c) {
    int off = c * 4096 + t * 16;
    int row = off >> 8;
    int ib  = off & 255;
    int swz = ib ^ ((row & 7) << 4);
    int grow = mb * 128 + row;
    uint4 va = make_uint4(0u, 0u, 0u, 0u);
    if (grow < N_NODES) va = *(const uint4*)(Asrc + (size_t)grow * 256 + ib);
    *(uint4*)(As + row * 256 + swz) = va;
    uint4 vb = *(const uint4*)(Bsrc + off);
    *(uint4*)(Bs + row * 256 + swz) = vb;
  }
  __syncthreads();
  const int wid = t >> 6, lane = t & 63;
  const int row0 = wid * 32;
  const int lr = lane & 15;
  const int kg = (lane >> 4) * 8;
  f32x4 acc[2][8];
  #pragma unroll
  for (int m = 0; m < 2; ++m)
    #pragma unroll
    for (int n = 0; n < 8; ++n) acc[m][n] = (f32x4)(0.f);
  #pragma unroll
  for (int kk = 0; kk < 4; ++kk) {
    const int kb = (kk * 32 + kg) * 2;
    s16x8 a[2], b[8];
    #pragma unroll
    for (int m = 0; m < 2; ++m) {
      int r = row0 + m * 16 + lr;
      a[m] = *(const s16x8*)(As + r * 256 + (kb ^ ((r & 7) << 4)));
    }
    #pragma unroll
    for (int n = 0; n < 8; ++n) {
      int cc = n * 16 + lr;
      b[n] = *(const s16x8*)(Bs + cc * 256 + (kb ^ ((cc & 7) << 4)));
    }
    #pragma unroll
    for (int m = 0; m < 2; ++m)
      #pragma unroll
      for (int n = 0; n < 8; ++n)
        acc[m][n] = __builtin_amdgcn_mfma_f32_16x16x32_bf16(a[m], b[n], acc[m][n], 0, 0, 0);
  }
  #pragma unroll
  for (int m = 0; m < 2; ++m) {
    int rbase = mb * 128 + row0 + m * 16 + (lane >> 4) * 4;
    #pragma unroll
    for (int n = 0; n < 8; ++n) {
      int col = n * 16 + lr;
      #pragma unroll
      for (int j = 0; j < 4; ++j) {
        int grow = rbase + j;
        if (grow < N_NODES)
          X[((size_t)rel * N_NODES + grow) * 128 + col] = f2bf(acc[m][n][j]);
      }
    }
  }
}

// ---- per-node aggregation over CSR: one wave per node, 2 f32 acc cols/lane ----
template <bool LAST>
__global__ void k_aggregate(const unsigned short* __restrict__ X,
                            const unsigned* __restrict__ keys,
                            const int* __restrict__ rowptr,
                            const float* __restrict__ bias,
                            void* __restrict__ out) {
  const int t = threadIdx.x;
  const int v = blockIdx.x * 4 + (t >> 6);
  const int lane = t & 63;
  const int start = rowptr[v], end = rowptr[v + 1];
  const unsigned char* Xb = (const unsigned char*)X;
  float a0 = 0.f, a1 = 0.f;
  int e = start;
  int nend = start + ((end - start) & ~3);
  for (; e < nend; e += 4) {
    unsigned k0 = keys[e], k1 = keys[e + 1], k2 = keys[e + 2], k3 = keys[e + 3];
    unsigned p0 = *(const unsigned*)(Xb + ((size_t)k0 << 8) + lane * 4);
    unsigned p1 = *(const unsigned*)(Xb + ((size_t)k1 << 8) + lane * 4);
    unsigned p2 = *(const unsigned*)(Xb + ((size_t)k2 << 8) + lane * 4);
    unsigned p3 = *(const unsigned*)(Xb + ((size_t)k3 << 8) + lane * 4);
    a0 += __uint_as_float(p0 << 16); a1 += __uint_as_float(p0 & 0xffff0000u);
    a0 += __uint_as_float(p1 << 16); a1 += __uint_as_float(p1 & 0xffff0000u);
    a0 += __uint_as_float(p2 << 16); a1 += __uint_as_float(p2 & 0xffff0000u);
    a0 += __uint_as_float(p3 << 16); a1 += __uint_as_float(p3 & 0xffff0000u);
  }
  for (; e < end; ++e) {
    unsigned k = keys[e];
    unsigned p = *(const unsigned*)(Xb + ((size_t)k << 8) + lane * 4);
    a0 += __uint_as_float(p << 16); a1 += __uint_as_float(p & 0xffff0000u);
  }
  { // self-loop pseudo-relation row
    unsigned p = *(const unsigned*)(Xb + (((size_t)8 * N_NODES + v) << 8) + lane * 4);
    a0 += __uint_as_float(p << 16); a1 += __uint_as_float(p & 0xffff0000u);
  }
  const float2 bb = *(const float2*)(bias + lane * 2);
  a0 += bb.x; a1 += bb.y;
  if (LAST) {
    float2 o; o.x = a0; o.y = a1;
    *(float2*)((float*)out + (size_t)v * 128 + lane * 2) = o;
  } else {
    unsigned po = ((unsigned)f2bf(a1) << 16) | (unsigned)f2bf(a0);
    *(unsigned*)((unsigned short*)out + (size_t)v * 128 + lane * 2) = po;
  }
}

extern "C" void kernel_launch(void* const* d_in, const int* in_sizes, int n_in,
                              void* d_out, int out_size, void* d_ws, size_t ws_size,
                              hipStream_t stream) {
  const int*   nid  = (const int*)d_in[0];
  const int*   src  = (const int*)d_in[1];
  const int*   dst  = (const int*)d_in[2];
  const int*   et   = (const int*)d_in[3];
  const float* emb  = (const float*)d_in[4];
  const float* W    = (const float*)d_in[5];
  const float* Wl   = (const float*)d_in[6];
  const float* bias = (const float*)d_in[7];

  unsigned char* ws = (unsigned char*)d_ws;
  size_t off = 0;
  auto alloc = [&](size_t bytes) {
    void* p = ws + off;
    off = (off + bytes + 255) & ~(size_t)255;
    return p;
  };
  unsigned short* X    = (unsigned short*)alloc((size_t)NREL1 * N_NODES * HID * 2); // 115.2 MB
  unsigned short* h0   = (unsigned short*)alloc((size_t)N_NODES * HID * 2);         // 12.8 MB
  unsigned short* h1   = (unsigned short*)alloc((size_t)N_NODES * HID * 2);         // 12.8 MB
  unsigned short* Wt   = (unsigned short*)alloc((size_t)2 * NREL1 * 128 * 128 * 2); // 0.6 MB
  unsigned*       keys = (unsigned*)alloc((size_t)N_EDGES * 4);                     // 6.4 MB
  int*            rowp = (int*)alloc((size_t)(N_NODES + 1) * 4);
  int*            hist = (int*)alloc((size_t)TOT * 4);                              // 150 KB
  int*            cur  = (int*)alloc((size_t)TOT * 4);                              // 150 KB
  int*            bbas = (int*)alloc((size_t)(NB + 1) * 4);
  unsigned*       tmp  = (unsigned*)X;   // X is dead until GEMM; reuse as 6.4MB scratch

  k_convert_w<<<1152, 256, 0, stream>>>(W, Wl, Wt);
  k_gather_h0<<<(N_NODES * 32) / 256, 256, 0, stream>>>(nid, emb, h0);
  k_chunk_hist<<<NCH, 256, 0, stream>>>(dst, hist);
  k_csr_scan<<<1, 256, 0, stream>>>(hist, cur, bbas, rowp);
  k_chunk_scatter<<<NCH, 256, 0, stream>>>(src, dst, et, cur, tmp);
  k_bucket_finalize<<<NB, 256, 0, stream>>>(tmp, bbas, rowp, keys);

  dim3 ggrid(NREL1, (N_NODES + 127) / 128);
  // layer 0
  k_gemm<<<ggrid, 256, 0, stream>>>(h0, Wt, X);
  k_aggregate<false><<<N_NODES / 4, 256, 0, stream>>>(X, keys, rowp, bias, (void*)h1);
  // layer 1
  k_gemm<<<ggrid, 256, 0, stream>>>(h1, Wt + (size_t)NREL1 * 128 * 128, X);
  k_aggregate<true><<<N_NODES / 4, 256, 0, stream>>>(X, keys, rowp, bias + HID, (void*)d_out);
}